// Round 10
// baseline (191.667 us; speedup 1.0000x reference)
//
#include <hip/hip_runtime.h>
#include <hip/hip_bf16.h>

typedef __attribute__((ext_vector_type(8))) short bf16x8;
typedef __attribute__((ext_vector_type(4))) float f32x4;

#define B_SZ   1024
#define T_SZ   128
#define L_SZ   256
#define F_SZ   784
#define M_TOT  (B_SZ * T_SZ)            // 131072
#define BK     32
#define KSTEPS 25                       // ceil(784/32), tail zero-padded
#define KCHUNKS 100                     // 25*4 chunks of 8 k-values
#define BROWS  32                       // rows per block

#define WPRE_ELEMS (KSTEPS * 4 * L_SZ)  // 25600 bf16x8 elements
#define WPRE_BYTES (WPRE_ELEMS * 16)    // 409600
#define CDIFF_ELEMS (T_SZ * L_SZ)       // 32768
#define WS_NEED (WPRE_BYTES + CDIFF_ELEMS * 4)

__device__ __forceinline__ unsigned short f2bf(float f) {
    __hip_bfloat16 h = __float2bfloat16(f);   // RTNE
    return *reinterpret_cast<unsigned short*>(&h);
}

// ---------------- prep: W -> bf16 MFMA-fragment layout; cdiff = c0 - c1 ----
__global__ __launch_bounds__(256) void dn_prep(
    const float* __restrict__ W, const float* __restrict__ contrib,
    unsigned short* __restrict__ wpre, float* __restrict__ cdiff)
{
    const int gid = blockIdx.x * 256 + threadIdx.x;
    if (gid < WPRE_ELEMS) {
        const int leaf = gid & 255;
        const int kg   = (gid >> 8) & 3;
        const int ks   = gid >> 10;
        const int k0   = ks * BK + kg * 8;
        bf16x8 v;
        #pragma unroll
        for (int j = 0; j < 8; ++j) {
            const int k = k0 + j;
            const float f = (k < F_SZ) ? W[(size_t)leaf * F_SZ + k] : 0.f;
            v[j] = (short)f2bf(f);
        }
        *reinterpret_cast<bf16x8*>(wpre + (size_t)gid * 8) = v;
    } else {
        const int cid = gid - WPRE_ELEMS;
        if (cid < CDIFF_ELEMS)
            cdiff[cid] = contrib[(size_t)cid * 2] - contrib[(size_t)cid * 2 + 1];
    }
}

// ---------------- v9: phase-pipelined staging under the K-loop (T14) -------
// Block = 32 rows x 256 cols, 512 thr (8 waves, wave tile 32x32), 51.2 KB LDS
// -> 3 blocks/CU. The 100-kchunk strip is staged in 7 phases; phase p's
// global loads (1 f32x8 chunk/thread, 8 VGPR) are issued right after the
// barrier and fly UNDER phase p-1's 4 K-steps; cvt+LDS-write lands them just
// before the barrier. HBM reads thus stream concurrently with MFMA + L2
// W-traffic instead of occupying a dedicated serial phase (which cost ~65
// us/CU in v8's phase-serial schedule).
__global__ __launch_bounds__(512, 3) void dn_fused9(
    const float* __restrict__ x, const unsigned short* __restrict__ wpre,
    const float* __restrict__ bias, const float* __restrict__ cdiff,
    float* __restrict__ out)
{
    __shared__ __align__(16) unsigned char smem[KCHUNKS * BROWS * 16]; // 51.2 KB
    bf16x8* As = reinterpret_cast<bf16x8*>(smem);
    typedef float OtRow[264];
    OtRow* Ot = reinterpret_cast<OtRow*>(smem);

    const int tid  = threadIdx.x;
    const int lane = tid & 63;
    const int wid  = tid >> 6;          // 0..7 -> 32-col group
    const int lr   = lane & 15;
    const int kseg = lane >> 4;         // 0..3

    const int rowBase = blockIdx.x * BROWS;
    const int colBase = wid * 32;

    // stage mapping (phases 0..5): chunk = (srow, kc=16p+skc), 1 chunk/thread
    const int srow = tid >> 4;          // 0..31
    const int skc  = tid & 15;          // 0..15
    const float* sbase = x + (size_t)(rowBase + srow) * F_SZ;
    // tail phase (p=5 loads it): kc 96..97 only, tid<64
    const int trow = tid >> 1;          // 0..31
    const int tkc  = 96 + (tid & 1);    // 96..97

    f32x4 slo, shi;                     // in-flight stage regs (8 VGPR)

    // prologue: zero pad slots (kc 98,99), load+write phase 0, barrier
    if (tid < 64) {
        const int zr = tid >> 1, zk = 98 + (tid & 1);
        bf16x8 z;
        #pragma unroll
        for (int j = 0; j < 8; ++j) z[j] = 0;
        As[zk * BROWS + (zr ^ (zk & 7))] = z;
    }
    {
        const float* p0 = sbase + skc * 8;
        slo = *reinterpret_cast<const f32x4*>(p0);
        shi = *reinterpret_cast<const f32x4*>(p0 + 4);
        bf16x8 v;
        #pragma unroll
        for (int j = 0; j < 4; ++j) { v[j] = (short)f2bf(slo[j]); v[4+j] = (short)f2bf(shi[j]); }
        As[skc * BROWS + (srow ^ (skc & 7))] = v;
    }
    __syncthreads();

    // ---- phased K-loop ----
    const unsigned short* wpb = wpre + ((size_t)kseg * L_SZ + colBase + lr) * 8;

    f32x4 acc[2][2];
    #pragma unroll
    for (int mi = 0; mi < 2; ++mi)
        #pragma unroll
        for (int ni = 0; ni < 2; ++ni)
            acc[mi][ni] = (f32x4){0.f, 0.f, 0.f, 0.f};

    bf16x8 wcur[2], wnxt[2];
    wcur[0] = *reinterpret_cast<const bf16x8*>(wpb);
    wcur[1] = *reinterpret_cast<const bf16x8*>(wpb + 128);

    #pragma unroll
    for (int p = 0; p < 7; ++p) {
        // issue next phase's global loads (fly under this phase's K-steps)
        if (p < 5) {
            const float* pn = sbase + (16 * (p + 1) + skc) * 8;
            slo = *reinterpret_cast<const f32x4*>(pn);
            shi = *reinterpret_cast<const f32x4*>(pn + 4);
        } else if (p == 5) {
            if (tid < 64) {
                const float* pn = x + (size_t)(rowBase + trow) * F_SZ + tkc * 8;
                slo = *reinterpret_cast<const f32x4*>(pn);
                shi = *reinterpret_cast<const f32x4*>(pn + 4);
            }
        }

        // K-steps of this phase
        const int ks0 = 4 * p;
        const int ks1 = (p < 6) ? 4 * p + 4 : 25;
        #pragma unroll
        for (int ks = ks0; ks < ks1; ++ks) {
            if (ks + 1 < KSTEPS) {
                wnxt[0] = *reinterpret_cast<const bf16x8*>(wpb + (size_t)(ks + 1) * 8192);
                wnxt[1] = *reinterpret_cast<const bf16x8*>(wpb + (size_t)(ks + 1) * 8192 + 128);
            }
            const int kcr = ks * 4 + kseg;
            const bf16x8 a0 = As[kcr * BROWS + (lr ^ (kcr & 7))];
            const bf16x8 a1 = As[kcr * BROWS + ((16 + lr) ^ (kcr & 7))];

            acc[0][0] = __builtin_amdgcn_mfma_f32_16x16x32_bf16(a0, wcur[0], acc[0][0], 0, 0, 0);
            acc[0][1] = __builtin_amdgcn_mfma_f32_16x16x32_bf16(a0, wcur[1], acc[0][1], 0, 0, 0);
            acc[1][0] = __builtin_amdgcn_mfma_f32_16x16x32_bf16(a1, wcur[0], acc[1][0], 0, 0, 0);
            acc[1][1] = __builtin_amdgcn_mfma_f32_16x16x32_bf16(a1, wcur[1], acc[1][1], 0, 0, 0);
            wcur[0] = wnxt[0];
            wcur[1] = wnxt[1];
        }

        // land the staged chunk into LDS, then make it visible
        if (p < 5) {
            const int kc = 16 * (p + 1) + skc;
            bf16x8 v;
            #pragma unroll
            for (int j = 0; j < 4; ++j) { v[j] = (short)f2bf(slo[j]); v[4+j] = (short)f2bf(shi[j]); }
            As[kc * BROWS + (srow ^ (kc & 7))] = v;
        } else if (p == 5) {
            if (tid < 64) {
                bf16x8 v;
                #pragma unroll
                for (int j = 0; j < 4; ++j) { v[j] = (short)f2bf(slo[j]); v[4+j] = (short)f2bf(shi[j]); }
                As[tkc * BROWS + (trow ^ (tkc & 7))] = v;
            }
        }
        __syncthreads();   // phase p+1 visible; after p==6: safe to reuse as Ot
    }

    // ---- sp in place ----
    float spv[2][2][4];
    #pragma unroll
    for (int ni = 0; ni < 2; ++ni) {
        const float bb = bias[colBase + ni * 16 + lr];
        #pragma unroll
        for (int mi = 0; mi < 2; ++mi)
            #pragma unroll
            for (int r = 0; r < 4; ++r)
                spv[mi][ni][r] = fminf(fmaxf(acc[mi][ni][r] + bb, -1.f), 1.f);
    }

    const int erow = tid >> 4;          // 0..31
    const int ecol = (tid & 15) * 4;    // 0..60
    const size_t GOFF = (size_t)M_TOT * L_SZ;
    float* orow = out + (size_t)(rowBase + erow) * L_SZ;

    // ---- pass 1: sp -> LDS transpose -> contiguous store ----
    #pragma unroll
    for (int ni = 0; ni < 2; ++ni)
        #pragma unroll
        for (int mi = 0; mi < 2; ++mi)
            #pragma unroll
            for (int r = 0; r < 4; ++r)
                Ot[mi * 16 + kseg * 4 + r][colBase + ni * 16 + lr] = spv[mi][ni][r];
    __syncthreads();
    #pragma unroll
    for (int j = 0; j < 4; ++j) {
        const f32x4 v = *reinterpret_cast<const f32x4*>(&Ot[erow][ecol + 64 * j]);
        *reinterpret_cast<f32x4*>(orow + ecol + 64 * j) = v;
    }
    __syncthreads();

    // ---- pass 2: gini -> LDS transpose -> contiguous store ----
    #pragma unroll
    for (int ni = 0; ni < 2; ++ni) {
        const int col = colBase + ni * 16 + lr;
        #pragma unroll
        for (int mi = 0; mi < 2; ++mi)
            #pragma unroll
            for (int r = 0; r < 4; ++r) {
                const int t = (rowBase + mi * 16 + kseg * 4 + r) & (T_SZ - 1);
                const float d  = spv[mi][ni][r] * cdiff[t * L_SZ + col];
                const float ed = __expf(d);
                const float s2 = ed / (1.f + ed);
                Ot[mi * 16 + kseg * 4 + r][col] = fmaf(2.f * s2, 1.f - s2, 1.f);
            }
    }
    __syncthreads();
    #pragma unroll
    for (int j = 0; j < 4; ++j) {
        const f32x4 v = *reinterpret_cast<const f32x4*>(&Ot[erow][ecol + 64 * j]);
        *reinterpret_cast<f32x4*>(orow + GOFF + ecol + 64 * j) = v;
    }
}

// ---------------- v1 fallback (no workspace needed) ------------------------
__global__ __launch_bounds__(512) void dn_fused_v1(
    const float* __restrict__ x, const float* __restrict__ W,
    const float* __restrict__ bias, const float* __restrict__ contrib,
    float* __restrict__ out)
{
    __shared__ bf16x8 As[4][128];
    __shared__ bf16x8 Bs[4][L_SZ];

    const int tid    = threadIdx.x;
    const int lane   = tid & 63;
    const int wid    = tid >> 6;
    const int waveM  = wid >> 2;
    const int waveN  = wid & 3;
    const int blkRow = blockIdx.x * 128;
    const int ar = tid >> 2;
    const int ak = (tid & 3) * 8;
    const int wr = tid >> 1;
    const int wk = (tid & 1) * 16;
    const int laneRow = lane & 15;
    const int kgrp    = lane >> 4;

    f32x4 acc[4][4];
    #pragma unroll
    for (int i = 0; i < 4; ++i)
        #pragma unroll
        for (int j = 0; j < 4; ++j)
            acc[i][j] = (f32x4){0.f, 0.f, 0.f, 0.f};

    const float* xrow = x + (size_t)(blkRow + ar) * F_SZ;
    const float* wrow = W + (size_t)wr * F_SZ;
    const f32x4 zf = {0.f, 0.f, 0.f, 0.f};

    f32x4 xa0 = *reinterpret_cast<const f32x4*>(xrow + ak);
    f32x4 xa1 = *reinterpret_cast<const f32x4*>(xrow + ak + 4);
    f32x4 wa0 = *reinterpret_cast<const f32x4*>(wrow + wk);
    f32x4 wa1 = *reinterpret_cast<const f32x4*>(wrow + wk + 4);
    f32x4 wa2 = *reinterpret_cast<const f32x4*>(wrow + wk + 8);
    f32x4 wa3 = *reinterpret_cast<const f32x4*>(wrow + wk + 12);

    for (int ks = 0; ks < KSTEPS; ++ks) {
        bf16x8 av, wv0, wv1;
        #pragma unroll
        for (int j = 0; j < 4; ++j) {
            av[j]      = (short)f2bf(xa0[j]);
            av[4 + j]  = (short)f2bf(xa1[j]);
            wv0[j]     = (short)f2bf(wa0[j]);
            wv0[4 + j] = (short)f2bf(wa1[j]);
            wv1[j]     = (short)f2bf(wa2[j]);
            wv1[4 + j] = (short)f2bf(wa3[j]);
        }
        As[ak >> 3][ar] = av;
        Bs[wk >> 3][wr] = wv0;
        Bs[(wk >> 3) + 1][wr] = wv1;
        __syncthreads();

        if (ks + 1 < KSTEPS) {
            const int kb = (ks + 1) * BK;
            if (kb + ak < F_SZ) {
                xa0 = *reinterpret_cast<const f32x4*>(xrow + kb + ak);
                xa1 = *reinterpret_cast<const f32x4*>(xrow + kb + ak + 4);
            } else { xa0 = zf; xa1 = zf; }
            if (kb + wk < F_SZ) {
                wa0 = *reinterpret_cast<const f32x4*>(wrow + kb + wk);
                wa1 = *reinterpret_cast<const f32x4*>(wrow + kb + wk + 4);
                wa2 = *reinterpret_cast<const f32x4*>(wrow + kb + wk + 8);
                wa3 = *reinterpret_cast<const f32x4*>(wrow + kb + wk + 12);
            } else { wa0 = zf; wa1 = zf; wa2 = zf; wa3 = zf; }
        }

        bf16x8 af[4], bfv[4];
        #pragma unroll
        for (int mi = 0; mi < 4; ++mi)
            af[mi] = As[kgrp][waveM * 64 + mi * 16 + laneRow];
        #pragma unroll
        for (int ni = 0; ni < 4; ++ni)
            bfv[ni] = Bs[kgrp][waveN * 64 + ni * 16 + laneRow];
        #pragma unroll
        for (int mi = 0; mi < 4; ++mi)
            #pragma unroll
            for (int ni = 0; ni < 4; ++ni)
                acc[mi][ni] = __builtin_amdgcn_mfma_f32_16x16x32_bf16(
                    af[mi], bfv[ni], acc[mi][ni], 0, 0, 0);
        __syncthreads();
    }

    const size_t GOFF  = (size_t)M_TOT * L_SZ;
    const int    rbase = waveM * 64 + (lane >> 4) * 4;
    const int    cbase = waveN * 64 + laneRow;
    #pragma unroll
    for (int ni = 0; ni < 4; ++ni) {
        const int col = cbase + ni * 16;
        const float bb = bias[col];
        #pragma unroll
        for (int mi = 0; mi < 4; ++mi) {
            #pragma unroll
            for (int r = 0; r < 4; ++r) {
                const int m = blkRow + rbase + mi * 16 + r;
                const int t = m & (T_SZ - 1);
                float v  = acc[mi][ni][r] + bb;
                float sp = fminf(fmaxf(v, -1.f), 1.f);
                const float* cp = contrib + (size_t)(t * L_SZ + col) * 2;
                const float d  = sp * (cp[0] - cp[1]);
                const float ed = __expf(d);
                const float s  = ed / (1.f + ed);
                const float g  = fmaf(2.f * s, 1.f - s, 1.f);
                const size_t o = (size_t)m * L_SZ + col;
                out[o]        = sp;
                out[GOFF + o] = g;
            }
        }
    }
}

extern "C" void kernel_launch(void* const* d_in, const int* in_sizes, int n_in,
                              void* d_out, int out_size, void* d_ws, size_t ws_size,
                              hipStream_t stream) {
    const float* x       = (const float*)d_in[0];
    const float* W       = (const float*)d_in[1];
    const float* bias    = (const float*)d_in[2];
    const float* contrib = (const float*)d_in[3];
    float* out = (float*)d_out;

    if (ws_size >= (size_t)WS_NEED && d_ws != nullptr) {
        unsigned short* wpre  = (unsigned short*)d_ws;
        float*          cdiff = (float*)((char*)d_ws + WPRE_BYTES);
        const int prep_threads = WPRE_ELEMS + CDIFF_ELEMS;
        dn_prep<<<(prep_threads + 255) / 256, 256, 0, stream>>>(W, contrib, wpre, cdiff);
        dn_fused9<<<M_TOT / BROWS, 512, 0, stream>>>(x, wpre, bias, cdiff, out);
    } else {
        dn_fused_v1<<<M_TOT / 128, 512, 0, stream>>>(x, W, bias, contrib, out);
    }
}